// Round 4
// baseline (134.004 us; speedup 1.0000x reference)
//
#include <hip/hip_runtime.h>
#include <hip/hip_bf16.h>
#include <stdint.h>

// MinGRU: B=8, S=4096, I=512, H=512 (fp32 in/out)
// R3: gemm_gate with A-only LDS (32 KiB dbuf -> 2 blocks/CU), B (weights)
//     streamed L2->registers double-buffered; chunk_reduce fused into epilogue.
// K0: cvt x,Wz,Wh -> bf16 ; K1: gemm_gate -> packed (a,b) + chunk summaries
// K3: chunk_scan ; K4: scan_write

typedef __attribute__((ext_vector_type(8))) short short8;   // 8 bf16 = 4 VGPR
typedef __attribute__((ext_vector_type(4))) float f32x4;

#define AS1 __attribute__((address_space(1)))
#define AS3 __attribute__((address_space(3)))

__device__ inline void gload_lds16(const void* g, void* l) {
  __builtin_amdgcn_global_load_lds((AS1 uint32_t*)(g), (AS3 uint32_t*)(l), 16, 0, 0);
}

__device__ inline ushort f2bf(float f) {
  union { __hip_bfloat16 h; ushort u; } v;
  v.h = __float2bfloat16(f);
  return v.u;
}

// ---------------- K0: fp32 -> bf16 (x, W_z, W_h in one launch) ----------------
__global__ void cvt_all(const float* __restrict__ x,
                        const float* __restrict__ wz,
                        const float* __restrict__ wh,
                        ushort* __restrict__ xb,
                        ushort* __restrict__ wzb,
                        ushort* __restrict__ whb) {
  int i = blockIdx.x * 256 + threadIdx.x;
  for (; i < 4325376; i += 2048 * 256) {
    const float* s; ushort* d; int j;
    if (i < 4194304)      { s = x;  d = xb;  j = i; }
    else if (i < 4259840) { s = wz; d = wzb; j = i - 4194304; }
    else                  { s = wh; d = whb; j = i - 4259840; }
    float4 v = reinterpret_cast<const float4*>(s)[j];
    ushort4 o = make_ushort4(f2bf(v.x), f2bf(v.y), f2bf(v.z), f2bf(v.w));
    reinterpret_cast<ushort4*>(d)[j] = o;
  }
}

// ---------------- K1: GEMM + gate + fused chunk summaries ----------------
// grid (256, 8): m0 = bx*128, n0 = by*64. 4 waves 2x2; wave = 64 rows x 32
// h-cols of BOTH z and h~. LDS: A only, double-buffered 2 x 16 KiB = 32 KiB.
// B fragments: global->register, double-buffered across fully-unrolled kt.
__global__ __launch_bounds__(256) void gemm_gate(
    const ushort* __restrict__ xb,   // [32768,512] bf16
    const ushort* __restrict__ wzb,  // [512,512] bf16
    const ushort* __restrict__ whb,  // [512,512] bf16
    const float* __restrict__ b_z,
    const float* __restrict__ b_h,
    uint* __restrict__ ab,           // [32768,512] packed (a,b) bf16
    float2* __restrict__ ABc)        // [8,128,512] chunk summaries
{
  __shared__ __align__(16) char smem[32768];   // A0 | A1

  const int t  = threadIdx.x;
  const int w  = t >> 6;
  const int l  = t & 63;
  const int lm = l & 15;
  const int lk = l >> 4;
  const int wm = w >> 1, wn = w & 1;       // wave: rows wm*64.., cols wn*32..
  const int bx = blockIdx.x;
  const int m0 = bx * 128;
  const int n0 = blockIdx.y * 64;

  const int srow  = t >> 3;    // A staging: 32 rows per 4KiB issue
  const int sslot = t & 7;

  float bzv[2], bhv[2];
  #pragma unroll
  for (int n = 0; n < 2; ++n) {
    int col = n0 + wn * 32 + n * 16 + lm;
    bzv[n] = b_z[col];
    bhv[n] = b_h[col];
  }

  f32x4 accz[4][2], acch[4][2];
  #pragma unroll
  for (int m = 0; m < 4; ++m)
    #pragma unroll
    for (int n = 0; n < 2; ++n) {
      accz[m][n] = (f32x4){0.f, 0.f, 0.f, 0.f};
      acch[m][n] = (f32x4){0.f, 0.f, 0.f, 0.f};
    }

  // B fragment base pointers (per-lane): row = n0 + wn*32 + n*16 + lm,
  // elem offset lk*8 within the 64-elem K-window.
  const ushort* wzp = wzb + (size_t)(n0 + wn * 32 + lm) * 512 + lk * 8;
  const ushort* whp = whb + (size_t)(n0 + wn * 32 + lm) * 512 + lk * 8;

  short8 rz[2][2][2], rh[2][2][2];   // [sel][kk][n], all statically indexed

  auto stageA = [&](int sel, int kt) {
    char* As = smem + sel * 16384;
    const int k0 = kt * 64;
    #pragma unroll
    for (int j = 0; j < 4; ++j) {
      int row = j * 32 + srow;
      int gs  = sslot ^ (row & 7);
      gload_lds16(xb + (size_t)(m0 + row) * 512 + k0 + gs * 8, As + j * 4096 + w * 1024);
    }
  };

#define LOADB(sel, ktv)                                                        \
  _Pragma("unroll")                                                            \
  for (int kk = 0; kk < 2; ++kk) {                                             \
    _Pragma("unroll")                                                          \
    for (int n = 0; n < 2; ++n) {                                              \
      rz[sel][kk][n] = *(const short8*)(wzp + n * 8192 + (ktv) * 64 + kk * 32);\
      rh[sel][kk][n] = *(const short8*)(whp + n * 8192 + (ktv) * 64 + kk * 32);\
    }                                                                          \
  }

  stageA(0, 0);
  LOADB(0, 0);
  __syncthreads();

  #pragma unroll
  for (int kt = 0; kt < 8; ++kt) {
    const int sel = kt & 1;
    if (kt < 7) {
      stageA(sel ^ 1, kt + 1);
      LOADB(sel ^ 1, kt + 1);
    }
    const char* As = smem + sel * 16384;
    #pragma unroll
    for (int kk = 0; kk < 2; ++kk) {
      short8 af[4];
      const int soff = (((kk * 4 + lk) ^ (lm & 7)) << 4);
      #pragma unroll
      for (int m = 0; m < 4; ++m) {
        int row = wm * 64 + m * 16 + lm;
        af[m] = *(const short8*)(As + row * 128 + soff);
      }
      #pragma unroll
      for (int m = 0; m < 4; ++m)
        #pragma unroll
        for (int n = 0; n < 2; ++n) {
          accz[m][n] = __builtin_amdgcn_mfma_f32_16x16x32_bf16(af[m], rz[sel][kk][n], accz[m][n], 0, 0, 0);
          acch[m][n] = __builtin_amdgcn_mfma_f32_16x16x32_bf16(af[m], rh[sel][kk][n], acch[m][n], 0, 0, 0);
        }
    }
    __syncthreads();
  }
#undef LOADB

  // ---- gate epilogue: a = 1-z, b = z*h~ ; write packed bf16 pairs ----
  // C layout: row = lk*4 + j (within 16), col = lm (m89-verified).
  float av[4][4][2], bv[4][4][2];
  #pragma unroll
  for (int m = 0; m < 4; ++m) {
    #pragma unroll
    for (int j = 0; j < 4; ++j) {
      size_t grow = (size_t)(m0 + wm * 64 + m * 16 + lk * 4 + j);
      uint* po = ab + grow * 512 + n0 + wn * 32 + lm;
      #pragma unroll
      for (int n = 0; n < 2; ++n) {
        float uz = accz[m][n][j] + bzv[n];
        float uh = acch[m][n][j] + bhv[n];
        float z  = 1.f / (1.f + __expf(-uz));
        float a  = 1.f - z;
        float bb = z * uh;
        av[m][j][n] = a;
        bv[m][j][n] = bb;
        po[n * 16] = (uint)f2bf(a) | ((uint)f2bf(bb) << 16);
      }
    }
  }

  // ---- fused chunk summaries: wave rows = 2 chunks of 32 ----
  // chunk cb in {0,1}: m = 2*cb + mm. Thread's 4-row segment at rows lk*4+j.
  // Compose order: mm asc, lk asc, j asc (= time ascending).
  #pragma unroll
  for (int cb = 0; cb < 2; ++cb) {
    #pragma unroll
    for (int n = 0; n < 2; ++n) {
      float At[2], Bt[2];
      #pragma unroll
      for (int mm = 0; mm < 2; ++mm) {
        float A = 1.f, Bv = 0.f;
        #pragma unroll
        for (int j = 0; j < 4; ++j) {
          float a = av[2 * cb + mm][j][n];
          float b = bv[2 * cb + mm][j][n];
          A  = a * A;
          Bv = a * Bv + b;
        }
        // gather the 4 lk-segments in order
        float Ag = 1.f, Bg = 0.f;
        #pragma unroll
        for (int q = 0; q < 4; ++q) {
          float Aq = __shfl(A,  lm + 16 * q);
          float Bq = __shfl(Bv, lm + 16 * q);
          Ag = Aq * Ag;
          Bg = Aq * Bg + Bq;
        }
        At[mm] = Ag;
        Bt[mm] = Bg;
      }
      float Achunk = At[1] * At[0];
      float Bchunk = At[1] * Bt[0] + Bt[1];
      if (lk == 0) {
        int bidx = bx >> 5;                       // batch
        int c    = (bx & 31) * 4 + wm * 2 + cb;   // chunk within batch
        int col  = n0 + wn * 32 + n * 16 + lm;
        ABc[((size_t)bidx * 128 + c) * 512 + col] = make_float2(Achunk, Bchunk);
      }
    }
  }
}

// ---------------- K3: sequential scan over chunk summaries ----------------
__global__ void chunk_scan(const float2* __restrict__ ABc,
                           const float* __restrict__ h0,
                           float* __restrict__ Hinit)
{
  int tid = blockIdx.x * 256 + threadIdx.x;   // 4096 total
  int h = tid & 511;
  int b = tid >> 9;
  float hv = h0[b * 512 + h];
  #pragma unroll 8
  for (int c = 0; c < 128; ++c) {
    size_t off = ((size_t)b * 128 + c) * 512 + h;
    Hinit[off] = hv;                 // h entering chunk c
    float2 s = ABc[off];
    hv = s.x * hv + s.y;
  }
}

// ---------------- K4: replay each chunk from Hinit, write out ----------------
__global__ void scan_write(const uint* __restrict__ ab,
                           const float* __restrict__ Hinit,
                           float* __restrict__ out)
{
  int tid = blockIdx.x * 256 + threadIdx.x;
  int h = tid & 511;
  int c = (tid >> 9) & 127;
  int b = tid >> 16;
  const uint* p = ab + ((size_t)b * 4096 + c * 32) * 512 + h;
  float* po = out + ((size_t)b * 4096 + c * 32) * 512 + h;
  float hv = Hinit[((size_t)b * 128 + c) * 512 + h];
  #pragma unroll 4
  for (int tt = 0; tt < 32; ++tt) {
    uint u = *p;
    float a  = __uint_as_float(u << 16);
    float bb = __uint_as_float(u & 0xffff0000u);
    hv = a * hv + bb;
    *po = hv;
    p += 512;
    po += 512;
  }
}

extern "C" void kernel_launch(void* const* d_in, const int* in_sizes, int n_in,
                              void* d_out, int out_size, void* d_ws, size_t ws_size,
                              hipStream_t stream) {
  const float* x   = (const float*)d_in[0];
  const float* h0  = (const float*)d_in[1];
  const float* W_z = (const float*)d_in[2];
  const float* b_z = (const float*)d_in[3];
  const float* W_h = (const float*)d_in[4];
  const float* b_h = (const float*)d_in[5];
  float* out = (float*)d_out;

  char* ws = (char*)d_ws;
  ushort* xb    = (ushort*)(ws);                  // 33,554,432 B
  ushort* wzb   = (ushort*)(ws + 33554432);       //    524,288 B
  ushort* whb   = (ushort*)(ws + 34078720);       //    524,288 B
  uint*   ab    = (uint*)  (ws + 34603008);       // 67,108,864 B
  float2* ABc   = (float2*)(ws + 101711872);      //  4,194,304 B
  float*  Hinit = (float*) (ws + 105906176);      //  2,097,152 B  (end: 108,003,328)

  cvt_all<<<2048, 256, 0, stream>>>(x, W_z, W_h, xb, wzb, whb);
  gemm_gate<<<dim3(256, 8), 256, 0, stream>>>(xb, wzb, whb, b_z, b_h, ab, ABc);
  chunk_scan<<<16, 256, 0, stream>>>(ABc, h0, Hinit);
  scan_write<<<2048, 256, 0, stream>>>(ab, Hinit, out);
}

// Round 5
// 103.449 us; speedup vs baseline: 1.2954x; 1.2954x over previous
//
#include <hip/hip_runtime.h>
#include <hip/hip_bf16.h>
#include <stdint.h>

// MinGRU: B=8, S=4096, I=512, H=512 (fp32 in/out)
// R4: gemm = R0's proven single-buffer 32KiB schedule + fused gate + fused
//     chunk summaries (ABc layout [b][h][c]); chunk_scan = 64-lane shfl scan;
//     scan_write = float4/uint4 vectorized (4 h-cols per thread).

typedef __attribute__((ext_vector_type(8))) short short8;   // 8 bf16 = 4 VGPR
typedef __attribute__((ext_vector_type(4))) float f32x4;

#define AS1 __attribute__((address_space(1)))
#define AS3 __attribute__((address_space(3)))

__device__ inline void gload_lds16(const void* g, void* l) {
  __builtin_amdgcn_global_load_lds((AS1 uint32_t*)(g), (AS3 uint32_t*)(l), 16, 0, 0);
}

__device__ inline ushort f2bf(float f) {
  union { __hip_bfloat16 h; ushort u; } v;
  v.h = __float2bfloat16(f);
  return v.u;
}

// ---------------- K0: fp32 -> bf16 (x, W_z, W_h in one launch) ----------------
__global__ void cvt_all(const float* __restrict__ x,
                        const float* __restrict__ wz,
                        const float* __restrict__ wh,
                        ushort* __restrict__ xb,
                        ushort* __restrict__ wzb,
                        ushort* __restrict__ whb) {
  int i = blockIdx.x * 256 + threadIdx.x;
  for (; i < 4325376; i += 2048 * 256) {
    const float* s; ushort* d; int j;
    if (i < 4194304)      { s = x;  d = xb;  j = i; }
    else if (i < 4259840) { s = wz; d = wzb; j = i - 4194304; }
    else                  { s = wh; d = whb; j = i - 4259840; }
    float4 v = reinterpret_cast<const float4*>(s)[j];
    ushort4 o = make_ushort4(f2bf(v.x), f2bf(v.y), f2bf(v.z), f2bf(v.w));
    reinterpret_cast<ushort4*>(d)[j] = o;
  }
}

// ---------------- K1: GEMM + gate + fused chunk summaries ----------------
// grid (256, 8): m0 = bx*128, n0 = by*64. 4 waves 2x2; wave = 64 rows x 32
// h-cols of BOTH z and h~. LDS single-buffered: A 16K | Bz 8K | Bh 8K = 32 KiB.
// R0's 2-barrier schedule (stage -> barrier -> compute -> barrier).
__global__ __launch_bounds__(256) void gemm_gate(
    const ushort* __restrict__ xb,   // [32768,512] bf16
    const ushort* __restrict__ wzb,  // [512,512] bf16
    const ushort* __restrict__ whb,  // [512,512] bf16
    const float* __restrict__ b_z,
    const float* __restrict__ b_h,
    uint* __restrict__ ab,           // [32768,512] packed (a,b) bf16
    float2* __restrict__ ABc)        // [8,512,128] chunk summaries (b,h,c)
{
  __shared__ __align__(16) char smem[32768];
  char* As  = smem;            // 128 x 64 bf16
  char* Bzs = smem + 16384;    //  64 x 64 bf16
  char* Bhs = smem + 24576;    //  64 x 64 bf16

  const int t  = threadIdx.x;
  const int w  = t >> 6;
  const int l  = t & 63;
  const int lm = l & 15;
  const int lk = l >> 4;
  const int wm = w >> 1, wn = w & 1;       // wave: rows wm*64.., cols wn*32..
  const int bx = blockIdx.x;
  const int m0 = bx * 128;
  const int n0 = blockIdx.y * 64;

  const int srow  = t >> 3;    // staging: 32 rows per 4KiB issue
  const int sslot = t & 7;

  float bzv[2], bhv[2];
  #pragma unroll
  for (int n = 0; n < 2; ++n) {
    int col = n0 + wn * 32 + n * 16 + lm;
    bzv[n] = b_z[col];
    bhv[n] = b_h[col];
  }

  f32x4 accz[4][2], acch[4][2];
  #pragma unroll
  for (int m = 0; m < 4; ++m)
    #pragma unroll
    for (int n = 0; n < 2; ++n) {
      accz[m][n] = (f32x4){0.f, 0.f, 0.f, 0.f};
      acch[m][n] = (f32x4){0.f, 0.f, 0.f, 0.f};
    }

  for (int kt = 0; kt < 8; ++kt) {
    const int k0 = kt * 64;
    #pragma unroll
    for (int j = 0; j < 4; ++j) {          // A: 4 x 4KiB issues (128 rows)
      int row = j * 32 + srow;
      int gs  = sslot ^ (row & 7);
      gload_lds16(xb + (size_t)(m0 + row) * 512 + k0 + gs * 8, As + j * 4096 + w * 1024);
    }
    #pragma unroll
    for (int j = 0; j < 2; ++j) {          // Bz,Bh: 2 issues each (64 rows)
      int row = j * 32 + srow;
      int gs  = sslot ^ (row & 7);
      gload_lds16(wzb + (size_t)(n0 + row) * 512 + k0 + gs * 8, Bzs + j * 4096 + w * 1024);
      gload_lds16(whb + (size_t)(n0 + row) * 512 + k0 + gs * 8, Bhs + j * 4096 + w * 1024);
    }
    __syncthreads();   // drains vmcnt (compiler) + barrier

    #pragma unroll
    for (int kk = 0; kk < 2; ++kk) {
      short8 af[4], bfz[2], bfh[2];
      const int soff = (((kk * 4 + lk) ^ (lm & 7)) << 4);
      #pragma unroll
      for (int m = 0; m < 4; ++m) {
        int row = wm * 64 + m * 16 + lm;
        af[m] = *(const short8*)(As + row * 128 + soff);
      }
      #pragma unroll
      for (int n = 0; n < 2; ++n) {
        int row = wn * 32 + n * 16 + lm;
        bfz[n] = *(const short8*)(Bzs + row * 128 + soff);
        bfh[n] = *(const short8*)(Bhs + row * 128 + soff);
      }
      #pragma unroll
      for (int m = 0; m < 4; ++m)
        #pragma unroll
        for (int n = 0; n < 2; ++n) {
          accz[m][n] = __builtin_amdgcn_mfma_f32_16x16x32_bf16(af[m], bfz[n], accz[m][n], 0, 0, 0);
          acch[m][n] = __builtin_amdgcn_mfma_f32_16x16x32_bf16(af[m], bfh[n], acch[m][n], 0, 0, 0);
        }
    }
    __syncthreads();
  }

  // ---- gate epilogue: a = 1-z, b = z*h~ ; packed bf16 pairs ----
  // C layout: row = lk*4 + j (within 16), col = lm (m89-verified).
  float av[4][4][2], bv[4][4][2];
  #pragma unroll
  for (int m = 0; m < 4; ++m) {
    #pragma unroll
    for (int j = 0; j < 4; ++j) {
      size_t grow = (size_t)(m0 + wm * 64 + m * 16 + lk * 4 + j);
      uint* po = ab + grow * 512 + n0 + wn * 32 + lm;
      #pragma unroll
      for (int n = 0; n < 2; ++n) {
        float uz = accz[m][n][j] + bzv[n];
        float uh = acch[m][n][j] + bhv[n];
        float z  = 1.f / (1.f + __expf(-uz));
        float a  = 1.f - z;
        float bb = z * uh;
        av[m][j][n] = a;
        bv[m][j][n] = bb;
        po[n * 16] = (uint)f2bf(a) | ((uint)f2bf(bb) << 16);
      }
    }
  }

  // ---- fused chunk summaries: wave rows = 2 chunks of 32 (time asc:
  // mm asc, lk asc, j asc). ABc layout: [b][h][c].
  #pragma unroll
  for (int cb = 0; cb < 2; ++cb) {
    #pragma unroll
    for (int n = 0; n < 2; ++n) {
      float At[2], Bt[2];
      #pragma unroll
      for (int mm = 0; mm < 2; ++mm) {
        float A = 1.f, Bv = 0.f;
        #pragma unroll
        for (int j = 0; j < 4; ++j) {
          float a = av[2 * cb + mm][j][n];
          float b = bv[2 * cb + mm][j][n];
          A  = a * A;
          Bv = a * Bv + b;
        }
        float Ag = 1.f, Bg = 0.f;
        #pragma unroll
        for (int q = 0; q < 4; ++q) {     // lk-segments in time order
          float Aq = __shfl(A,  lm + 16 * q);
          float Bq = __shfl(Bv, lm + 16 * q);
          Ag = Aq * Ag;
          Bg = Aq * Bg + Bq;
        }
        At[mm] = Ag;
        Bt[mm] = Bg;
      }
      float Achunk = At[1] * At[0];
      float Bchunk = At[1] * Bt[0] + Bt[1];
      if (lk == 0) {
        int bidx = bx >> 5;                       // batch
        int c    = (bx & 31) * 4 + wm * 2 + cb;   // chunk within batch
        int col  = n0 + wn * 32 + n * 16 + lm;
        ABc[((size_t)bidx * 512 + col) * 128 + c] = make_float2(Achunk, Bchunk);
      }
    }
  }
}

// ---------------- K3: wave-parallel scan over chunk summaries ----------------
// One 64-lane wave per (b,h) chain of 128 chunks: two half-scans + splice.
// compose(prev,cur) = (prev.A*cur.A, cur.A*prev.B + cur.B).
__global__ __launch_bounds__(256) void chunk_scan(
    const float2* __restrict__ ABc,   // [8,512,128]
    const float* __restrict__ h0,
    float* __restrict__ Hinit)        // [8,128,512]
{
  __shared__ float sm[128][4];
  const int w = threadIdx.x >> 6, l = threadIdx.x & 63;
  const int b   = blockIdx.x >> 7;
  const int h0g = (blockIdx.x & 127) * 4;
  const int h   = h0g + w;

  const float2* base = ABc + ((size_t)b * 512 + h) * 128;
  float2 s1 = base[l];
  float2 s2 = base[64 + l];

  // inclusive scan, half 1 (chunks 0..63)
  float A1 = s1.x, B1 = s1.y;
  #pragma unroll
  for (int d = 1; d < 64; d <<= 1) {
    float uA = __shfl_up(A1, d);
    float uB = __shfl_up(B1, d);
    if (l >= d) { B1 = A1 * uB + B1; A1 = A1 * uA; }
  }
  // inclusive scan, half 2 (chunks 64..127, local)
  float A2 = s2.x, B2 = s2.y;
  #pragma unroll
  for (int d = 1; d < 64; d <<= 1) {
    float uA = __shfl_up(A2, d);
    float uB = __shfl_up(B2, d);
    if (l >= d) { B2 = A2 * uB + B2; A2 = A2 * uA; }
  }
  float PA = __shfl(A1, 63), PB = __shfl(B1, 63);   // prefix of chunks 0..63
  float FA = A2 * PA;                               // full prefix 0..64+l
  float FB = A2 * PB + B2;

  // exclusive prefixes -> h entering each chunk
  float e1A = __shfl_up(A1, 1), e1B = __shfl_up(B1, 1);
  if (l == 0) { e1A = 1.f; e1B = 0.f; }
  float e2A = __shfl_up(FA, 1), e2B = __shfl_up(FB, 1);
  if (l == 0) { e2A = PA; e2B = PB; }

  float h0v = h0[b * 512 + h];
  sm[l][w]      = e1A * h0v + e1B;
  sm[64 + l][w] = e2A * h0v + e2B;
  __syncthreads();

  const int t = threadIdx.x;
  if (t < 128) {
    float4 v = *(const float4*)sm[t];
    *(float4*)(Hinit + ((size_t)b * 128 + t) * 512 + h0g) = v;
  }
}

// ---------------- K4: replay each chunk from Hinit, write out ----------------
// 4 h-columns per thread: uint4 in, float4 out (16B/lane).
__global__ __launch_bounds__(256) void scan_write(
    const uint* __restrict__ ab,
    const float* __restrict__ Hinit,
    float* __restrict__ out)
{
  int tid = blockIdx.x * 256 + threadIdx.x;   // 131072
  int cg = tid & 127;            // h-group: h = cg*4 ..
  int c  = (tid >> 7) & 127;
  int b  = tid >> 14;
  const uint4* p = reinterpret_cast<const uint4*>(ab + ((size_t)(b * 4096 + c * 32)) * 512) + cg;
  float4 hv = *reinterpret_cast<const float4*>(Hinit + ((size_t)b * 128 + c) * 512 + cg * 4);
  float4* po = reinterpret_cast<float4*>(out + ((size_t)(b * 4096 + c * 32)) * 512) + cg;
  #pragma unroll 4
  for (int t = 0; t < 32; ++t) {
    uint4 u = p[(size_t)t * 128];
    hv.x = __uint_as_float(u.x << 16) * hv.x + __uint_as_float(u.x & 0xffff0000u);
    hv.y = __uint_as_float(u.y << 16) * hv.y + __uint_as_float(u.y & 0xffff0000u);
    hv.z = __uint_as_float(u.z << 16) * hv.z + __uint_as_float(u.z & 0xffff0000u);
    hv.w = __uint_as_float(u.w << 16) * hv.w + __uint_as_float(u.w & 0xffff0000u);
    po[(size_t)t * 128] = hv;
  }
}

extern "C" void kernel_launch(void* const* d_in, const int* in_sizes, int n_in,
                              void* d_out, int out_size, void* d_ws, size_t ws_size,
                              hipStream_t stream) {
  const float* x   = (const float*)d_in[0];
  const float* h0  = (const float*)d_in[1];
  const float* W_z = (const float*)d_in[2];
  const float* b_z = (const float*)d_in[3];
  const float* W_h = (const float*)d_in[4];
  const float* b_h = (const float*)d_in[5];
  float* out = (float*)d_out;

  char* ws = (char*)d_ws;
  ushort* xb    = (ushort*)(ws);                  // 33,554,432 B
  ushort* wzb   = (ushort*)(ws + 33554432);       //    524,288 B
  ushort* whb   = (ushort*)(ws + 34078720);       //    524,288 B
  uint*   ab    = (uint*)  (ws + 34603008);       // 67,108,864 B
  float2* ABc   = (float2*)(ws + 101711872);      //  4,194,304 B  [8,512,128]
  float*  Hinit = (float*) (ws + 105906176);      //  2,097,152 B  [8,128,512]

  cvt_all<<<2048, 256, 0, stream>>>(x, W_z, W_h, xb, wzb, whb);
  gemm_gate<<<dim3(256, 8), 256, 0, stream>>>(xb, wzb, whb, b_z, b_h, ab, ABc);
  chunk_scan<<<1024, 256, 0, stream>>>(ABc, h0, Hinit);
  scan_write<<<512, 256, 0, stream>>>(ab, Hinit, out);
}

// Round 6
// 99.002 us; speedup vs baseline: 1.3535x; 1.0449x over previous
//
#include <hip/hip_runtime.h>
#include <hip/hip_bf16.h>
#include <stdint.h>

// MinGRU: B=8, S=4096, I=512, H=512 (fp32 in/out)
// R5: gemm -> counted-vmcnt double-buffered pipeline at BK=32 (32 KiB LDS,
//     2 blocks/CU): STAGE(next); vmcnt(4); s_barrier; ds_read+MFMA; s_barrier.
//     Never drains vmcnt to 0 in the main loop (T3/T4 minimum recipe).
//     Other kernels unchanged from R4 (at memory floor).

typedef __attribute__((ext_vector_type(8))) short short8;   // 8 bf16 = 4 VGPR
typedef __attribute__((ext_vector_type(4))) float f32x4;

#define AS1 __attribute__((address_space(1)))
#define AS3 __attribute__((address_space(3)))

__device__ inline void gload_lds16(const void* g, void* l) {
  __builtin_amdgcn_global_load_lds((AS1 uint32_t*)(g), (AS3 uint32_t*)(l), 16, 0, 0);
}

__device__ inline ushort f2bf(float f) {
  union { __hip_bfloat16 h; ushort u; } v;
  v.h = __float2bfloat16(f);
  return v.u;
}

// ---------------- K0: fp32 -> bf16 (x, W_z, W_h in one launch) ----------------
__global__ void cvt_all(const float* __restrict__ x,
                        const float* __restrict__ wz,
                        const float* __restrict__ wh,
                        ushort* __restrict__ xb,
                        ushort* __restrict__ wzb,
                        ushort* __restrict__ whb) {
  int i = blockIdx.x * 256 + threadIdx.x;
  for (; i < 4325376; i += 2048 * 256) {
    const float* s; ushort* d; int j;
    if (i < 4194304)      { s = x;  d = xb;  j = i; }
    else if (i < 4259840) { s = wz; d = wzb; j = i - 4194304; }
    else                  { s = wh; d = whb; j = i - 4259840; }
    float4 v = reinterpret_cast<const float4*>(s)[j];
    ushort4 o = make_ushort4(f2bf(v.x), f2bf(v.y), f2bf(v.z), f2bf(v.w));
    reinterpret_cast<ushort4*>(d)[j] = o;
  }
}

// ---------------- K1: GEMM + gate + fused chunk summaries ----------------
// grid (256, 8): m0 = bx*128, n0 = by*64. 4 waves 2x2; wave = 64 rows x 32
// h-cols of BOTH z and h~. LDS: 2 x (A 8K | Bz 4K | Bh 4K) = 32 KiB.
// BK=32, 16 K-steps, counted vmcnt(4) pipeline with raw s_barrier.
// Swizzle: 4 slots of 16B per 64B row; slot ^= (row>>1)&3 (2-way max = free).
__global__ __launch_bounds__(256) void gemm_gate(
    const ushort* __restrict__ xb,   // [32768,512] bf16
    const ushort* __restrict__ wzb,  // [512,512] bf16
    const ushort* __restrict__ whb,  // [512,512] bf16
    const float* __restrict__ b_z,
    const float* __restrict__ b_h,
    uint* __restrict__ ab,           // [32768,512] packed (a,b) bf16
    float2* __restrict__ ABc)        // [8,512,128] chunk summaries (b,h,c)
{
  __shared__ __align__(16) char smem[32768];
  // per sel (16 KiB): A [0,8192) = 128x32 bf16, Bz [8192,12288), Bh [12288,16384)

  const int t  = threadIdx.x;
  const int w  = t >> 6;
  const int l  = t & 63;
  const int lm = l & 15;
  const int lk = l >> 4;
  const int wm = w >> 1, wn = w & 1;       // wave: rows wm*64.., cols wn*32..
  const int bx = blockIdx.x;
  const int m0 = bx * 128;
  const int n0 = blockIdx.y * 64;

  const int srow = t >> 2;     // 0..63 rows per issue
  const int ssl  = t & 3;      // 16B slot within 64B row

  f32x4 accz[4][2], acch[4][2];
  #pragma unroll
  for (int m = 0; m < 4; ++m)
    #pragma unroll
    for (int n = 0; n < 2; ++n) {
      accz[m][n] = (f32x4){0.f, 0.f, 0.f, 0.f};
      acch[m][n] = (f32x4){0.f, 0.f, 0.f, 0.f};
    }

  // Exactly 4 gload_lds per stage; NO other vmcnt ops inside the loop
  // (bias loads deferred to the epilogue) so vmcnt counts stay exact.
  auto stage = [&](int sel, int kt) {
    char* base = smem + sel * 16384;
    const int k0 = kt * 32;
    #pragma unroll
    for (int j = 0; j < 2; ++j) {          // A: 2 x 4KiB issues (64 rows each)
      int row = j * 64 + srow;
      int gs  = ssl ^ ((row >> 1) & 3);
      gload_lds16(xb + (size_t)(m0 + row) * 512 + k0 + gs * 8,
                  base + j * 4096 + w * 1024);
    }
    {
      int row = srow;
      int gs  = ssl ^ ((row >> 1) & 3);
      gload_lds16(wzb + (size_t)(n0 + row) * 512 + k0 + gs * 8,
                  base + 8192 + w * 1024);
      gload_lds16(whb + (size_t)(n0 + row) * 512 + k0 + gs * 8,
                  base + 12288 + w * 1024);
    }
  };

  stage(0, 0);                              // 4 outstanding

  #pragma unroll
  for (int kt = 0; kt < 16; ++kt) {
    const int sel = kt & 1;
    if (kt < 15) {
      stage(sel ^ 1, kt + 1);               // 8 outstanding
      asm volatile("s_waitcnt vmcnt(4)" ::: "memory");   // cur tile landed
    } else {
      asm volatile("s_waitcnt vmcnt(0)" ::: "memory");   // last tile
    }
    __builtin_amdgcn_s_barrier();           // raw: no compiler vmcnt(0) drain

    const char* base = smem + sel * 16384;
    short8 af[4], bfz[2], bfh[2];
    #pragma unroll
    for (int m = 0; m < 4; ++m) {
      int row = wm * 64 + m * 16 + lm;
      af[m] = *(const short8*)(base + row * 64 + ((lk ^ ((row >> 1) & 3)) << 4));
    }
    #pragma unroll
    for (int n = 0; n < 2; ++n) {
      int row = wn * 32 + n * 16 + lm;
      int so  = ((lk ^ ((row >> 1) & 3)) << 4);
      bfz[n] = *(const short8*)(base + 8192  + row * 64 + so);
      bfh[n] = *(const short8*)(base + 12288 + row * 64 + so);
    }
    __builtin_amdgcn_s_setprio(1);
    #pragma unroll
    for (int m = 0; m < 4; ++m)
      #pragma unroll
      for (int n = 0; n < 2; ++n) {
        accz[m][n] = __builtin_amdgcn_mfma_f32_16x16x32_bf16(af[m], bfz[n], accz[m][n], 0, 0, 0);
        acch[m][n] = __builtin_amdgcn_mfma_f32_16x16x32_bf16(af[m], bfh[n], acch[m][n], 0, 0, 0);
      }
    __builtin_amdgcn_s_setprio(0);
    __builtin_amdgcn_s_barrier();           // protect buffer reuse next iter
  }

  // ---- bias loads (deferred so K-loop vmcnt stays exact) ----
  float bzv[2], bhv[2];
  #pragma unroll
  for (int n = 0; n < 2; ++n) {
    int col = n0 + wn * 32 + n * 16 + lm;
    bzv[n] = b_z[col];
    bhv[n] = b_h[col];
  }

  // ---- gate epilogue: a = 1-z, b = z*h~ ; packed bf16 pairs ----
  // C layout: row = lk*4 + j (within 16), col = lm (m89-verified).
  float av[4][4][2], bv[4][4][2];
  #pragma unroll
  for (int m = 0; m < 4; ++m) {
    #pragma unroll
    for (int j = 0; j < 4; ++j) {
      size_t grow = (size_t)(m0 + wm * 64 + m * 16 + lk * 4 + j);
      uint* po = ab + grow * 512 + n0 + wn * 32 + lm;
      #pragma unroll
      for (int n = 0; n < 2; ++n) {
        float uz = accz[m][n][j] + bzv[n];
        float uh = acch[m][n][j] + bhv[n];
        float z  = 1.f / (1.f + __expf(-uz));
        float a  = 1.f - z;
        float bb = z * uh;
        av[m][j][n] = a;
        bv[m][j][n] = bb;
        po[n * 16] = (uint)f2bf(a) | ((uint)f2bf(bb) << 16);
      }
    }
  }

  // ---- fused chunk summaries: wave rows = 2 chunks of 32 (time asc:
  // mm asc, lk asc, j asc). ABc layout: [b][h][c].
  #pragma unroll
  for (int cb = 0; cb < 2; ++cb) {
    #pragma unroll
    for (int n = 0; n < 2; ++n) {
      float At[2], Bt[2];
      #pragma unroll
      for (int mm = 0; mm < 2; ++mm) {
        float A = 1.f, Bv = 0.f;
        #pragma unroll
        for (int j = 0; j < 4; ++j) {
          float a = av[2 * cb + mm][j][n];
          float b = bv[2 * cb + mm][j][n];
          A  = a * A;
          Bv = a * Bv + b;
        }
        float Ag = 1.f, Bg = 0.f;
        #pragma unroll
        for (int q = 0; q < 4; ++q) {     // lk-segments in time order
          float Aq = __shfl(A,  lm + 16 * q);
          float Bq = __shfl(Bv, lm + 16 * q);
          Ag = Aq * Ag;
          Bg = Aq * Bg + Bq;
        }
        At[mm] = Ag;
        Bt[mm] = Bg;
      }
      float Achunk = At[1] * At[0];
      float Bchunk = At[1] * Bt[0] + Bt[1];
      if (lk == 0) {
        int bidx = bx >> 5;                       // batch
        int c    = (bx & 31) * 4 + wm * 2 + cb;   // chunk within batch
        int col  = n0 + wn * 32 + n * 16 + lm;
        ABc[((size_t)bidx * 512 + col) * 128 + c] = make_float2(Achunk, Bchunk);
      }
    }
  }
}

// ---------------- K3: wave-parallel scan over chunk summaries ----------------
// One 64-lane wave per (b,h) chain of 128 chunks: two half-scans + splice.
__global__ __launch_bounds__(256) void chunk_scan(
    const float2* __restrict__ ABc,   // [8,512,128]
    const float* __restrict__ h0,
    float* __restrict__ Hinit)        // [8,128,512]
{
  __shared__ float sm[128][4];
  const int w = threadIdx.x >> 6, l = threadIdx.x & 63;
  const int b   = blockIdx.x >> 7;
  const int h0g = (blockIdx.x & 127) * 4;
  const int h   = h0g + w;

  const float2* base = ABc + ((size_t)b * 512 + h) * 128;
  float2 s1 = base[l];
  float2 s2 = base[64 + l];

  float A1 = s1.x, B1 = s1.y;
  #pragma unroll
  for (int d = 1; d < 64; d <<= 1) {
    float uA = __shfl_up(A1, d);
    float uB = __shfl_up(B1, d);
    if (l >= d) { B1 = A1 * uB + B1; A1 = A1 * uA; }
  }
  float A2 = s2.x, B2 = s2.y;
  #pragma unroll
  for (int d = 1; d < 64; d <<= 1) {
    float uA = __shfl_up(A2, d);
    float uB = __shfl_up(B2, d);
    if (l >= d) { B2 = A2 * uB + B2; A2 = A2 * uA; }
  }
  float PA = __shfl(A1, 63), PB = __shfl(B1, 63);   // prefix of chunks 0..63
  float FA = A2 * PA;
  float FB = A2 * PB + B2;

  float e1A = __shfl_up(A1, 1), e1B = __shfl_up(B1, 1);
  if (l == 0) { e1A = 1.f; e1B = 0.f; }
  float e2A = __shfl_up(FA, 1), e2B = __shfl_up(FB, 1);
  if (l == 0) { e2A = PA; e2B = PB; }

  float h0v = h0[b * 512 + h];
  sm[l][w]      = e1A * h0v + e1B;
  sm[64 + l][w] = e2A * h0v + e2B;
  __syncthreads();

  const int tt = threadIdx.x;
  if (tt < 128) {
    float4 v = *(const float4*)sm[tt];
    *(float4*)(Hinit + ((size_t)b * 128 + tt) * 512 + h0g) = v;
  }
}

// ---------------- K4: replay each chunk from Hinit, write out ----------------
__global__ __launch_bounds__(256) void scan_write(
    const uint* __restrict__ ab,
    const float* __restrict__ Hinit,
    float* __restrict__ out)
{
  int tid = blockIdx.x * 256 + threadIdx.x;   // 131072
  int cg = tid & 127;            // h-group: h = cg*4 ..
  int c  = (tid >> 7) & 127;
  int b  = tid >> 14;
  const uint4* p = reinterpret_cast<const uint4*>(ab + ((size_t)(b * 4096 + c * 32)) * 512) + cg;
  float4 hv = *reinterpret_cast<const float4*>(Hinit + ((size_t)b * 128 + c) * 512 + cg * 4);
  float4* po = reinterpret_cast<float4*>(out + ((size_t)(b * 4096 + c * 32)) * 512) + cg;
  #pragma unroll 4
  for (int t = 0; t < 32; ++t) {
    uint4 u = p[(size_t)t * 128];
    hv.x = __uint_as_float(u.x << 16) * hv.x + __uint_as_float(u.x & 0xffff0000u);
    hv.y = __uint_as_float(u.y << 16) * hv.y + __uint_as_float(u.y & 0xffff0000u);
    hv.z = __uint_as_float(u.z << 16) * hv.z + __uint_as_float(u.z & 0xffff0000u);
    hv.w = __uint_as_float(u.w << 16) * hv.w + __uint_as_float(u.w & 0xffff0000u);
    po[(size_t)t * 128] = hv;
  }
}

extern "C" void kernel_launch(void* const* d_in, const int* in_sizes, int n_in,
                              void* d_out, int out_size, void* d_ws, size_t ws_size,
                              hipStream_t stream) {
  const float* x   = (const float*)d_in[0];
  const float* h0  = (const float*)d_in[1];
  const float* W_z = (const float*)d_in[2];
  const float* b_z = (const float*)d_in[3];
  const float* W_h = (const float*)d_in[4];
  const float* b_h = (const float*)d_in[5];
  float* out = (float*)d_out;

  char* ws = (char*)d_ws;
  ushort* xb    = (ushort*)(ws);                  // 33,554,432 B
  ushort* wzb   = (ushort*)(ws + 33554432);       //    524,288 B
  ushort* whb   = (ushort*)(ws + 34078720);       //    524,288 B
  uint*   ab    = (uint*)  (ws + 34603008);       // 67,108,864 B
  float2* ABc   = (float2*)(ws + 101711872);      //  4,194,304 B  [8,512,128]
  float*  Hinit = (float*) (ws + 105906176);      //  2,097,152 B  [8,128,512]

  cvt_all<<<2048, 256, 0, stream>>>(x, W_z, W_h, xb, wzb, whb);
  gemm_gate<<<dim3(256, 8), 256, 0, stream>>>(xb, wzb, whb, b_z, b_h, ab, ABc);
  chunk_scan<<<1024, 256, 0, stream>>>(ABc, h0, Hinit);
  scan_write<<<512, 256, 0, stream>>>(ab, Hinit, out);
}